// Round 1
// baseline (642.893 us; speedup 1.0000x reference)
//
#include <hip/hip_runtime.h>
#include <math.h>

#define NN 50000
#define NE 1000000
#define NH 64

// ---------------- pass 1: scatter X[src] into sum_nb[dst], count degrees ----
__global__ __launch_bounds__(256) void scatter_x(
    const float* __restrict__ X, const int* __restrict__ src,
    const int* __restrict__ dst, float* __restrict__ sumnb,
    float* __restrict__ cnt_dst, float* __restrict__ cnt_src) {
    long long tid = (long long)blockIdx.x * blockDim.x + threadIdx.x;
    int edge = (int)(tid >> 6);
    int lane = (int)(tid & 63);
    if (edge >= NE) return;
    int s = src[edge], d = dst[edge];
    atomicAdd(&sumnb[d * NH + lane], X[s * NH + lane]);
    if (lane == 0) {
        atomicAdd(&cnt_dst[d], 1.0f);
        atomicAdd(&cnt_src[s], 1.0f);
    }
}

// ---------------- pass 2: per-node H = relu(X Ws + mean Wn + b); A=H Q1; B=H Q2
__global__ __launch_bounds__(256) void node_pass(
    const float* __restrict__ X, const float* __restrict__ sumnb,
    const float* __restrict__ cnt_dst,
    const float* __restrict__ Wself, const float* __restrict__ Wneigh,
    const float* __restrict__ bsage, const float* __restrict__ Qw,
    float* __restrict__ A, float* __restrict__ B) {
    __shared__ float sWs[64 * 64];
    __shared__ float sWn[64 * 64];
    __shared__ float sQ1[64 * 64];
    __shared__ float sQ2[64 * 64];
    __shared__ float sx[4][64];
    __shared__ float sm[4][64];
    __shared__ float sh[4][64];

    for (int i = threadIdx.x; i < 64 * 64; i += 256) {
        sWs[i] = Wself[i];
        sWn[i] = Wneigh[i];
        sQ1[i] = Qw[i];            // rows 0..63 of Q_w
        sQ2[i] = Qw[4096 + i];     // rows 64..127
    }
    __syncthreads();

    int sub = threadIdx.x >> 6;   // node slot 0..3 in this block
    int j   = threadIdx.x & 63;   // output feature
    float bj = bsage[j];

    for (int base = blockIdx.x * 4; base < NN; base += gridDim.x * 4) {
        int node = base + sub;
        if (node < NN) {
            float c  = cnt_dst[node];
            sx[sub][j] = X[(long long)node * NH + j];
            sm[sub][j] = sumnb[(long long)node * NH + j] / fmaxf(c, 1.0f);
        }
        __syncthreads();
        if (node < NN) {
            float acc = bj;
            #pragma unroll
            for (int k = 0; k < 64; ++k)
                acc += sx[sub][k] * sWs[k * 64 + j] + sm[sub][k] * sWn[k * 64 + j];
            sh[sub][j] = fmaxf(acc, 0.0f);
        }
        __syncthreads();
        if (node < NN) {
            float a = 0.0f, b = 0.0f;
            #pragma unroll
            for (int k = 0; k < 64; ++k) {
                float h = sh[sub][k];
                a += h * sQ1[k * 64 + j];
                b += h * sQ2[k * 64 + j];
            }
            A[(long long)node * NH + j] = a;
            B[(long long)node * NH + j] = b;
        }
        __syncthreads();
    }
}

// ---------------- pass 3: per-edge e=(A[src]+B[dst]+Qb)^2, scatter into acc[src]
__global__ __launch_bounds__(256) void edge_pass(
    const float* __restrict__ A, const float* __restrict__ B,
    const float* __restrict__ Qb, const int* __restrict__ src,
    const int* __restrict__ dst, float* __restrict__ acc) {
    long long tid = (long long)blockIdx.x * blockDim.x + threadIdx.x;
    int edge = (int)(tid >> 6);
    int lane = (int)(tid & 63);
    if (edge >= NE) return;
    int s = src[edge], d = dst[edge];
    float e = A[(long long)s * NH + lane] + B[(long long)d * NH + lane] + Qb[lane];
    atomicAdd(&acc[(long long)s * NH + lane], e * e);
}

// ---------------- pass 4: out = tanh(acc / max(cnt_src,1)) -------------------
__global__ __launch_bounds__(256) void finalize(
    float* __restrict__ out, const float* __restrict__ cnt_src) {
    int tid = blockIdx.x * blockDim.x + threadIdx.x;
    if (tid >= NN * NH) return;
    int node = tid >> 6;
    float c = fmaxf(cnt_src[node], 1.0f);
    out[tid] = tanhf(out[tid] / c);
}

extern "C" void kernel_launch(void* const* d_in, const int* in_sizes, int n_in,
                              void* d_out, int out_size, void* d_ws, size_t ws_size,
                              hipStream_t stream) {
    const float* X      = (const float*)d_in[0];
    const int*   ei     = (const int*)d_in[1];   // [2, NE] int32
    const float* Wself  = (const float*)d_in[2];
    const float* Wneigh = (const float*)d_in[3];
    const float* bsage  = (const float*)d_in[4];
    const float* Qw     = (const float*)d_in[5];
    const float* Qb     = (const float*)d_in[6];
    const int* src = ei;
    const int* dst = ei + NE;

    float* out = (float*)d_out;

    // workspace layout (floats)
    float* ws      = (float*)d_ws;
    float* sumnb   = ws;                       // NN*NH = 3.2M
    float* A       = ws + (size_t)NN * NH;     // 3.2M
    float* B       = ws + (size_t)2 * NN * NH; // 3.2M
    float* cnt_dst = ws + (size_t)3 * NN * NH; // 50000 (padded to 50048)
    float* cnt_src = cnt_dst + 50048;          // 50000

    // zero accumulators (d_ws/d_out are poisoned, not re-zeroed between replays)
    hipMemsetAsync(sumnb, 0, (size_t)NN * NH * sizeof(float), stream);
    hipMemsetAsync(cnt_dst, 0, (size_t)(50048 + 50048) * sizeof(float), stream);
    hipMemsetAsync(out, 0, (size_t)NN * NH * sizeof(float), stream);

    // pass 1: neighbor-mean numerator + degrees
    {
        long long threads = (long long)NE * 64;
        int blocks = (int)((threads + 255) / 256);
        scatter_x<<<blocks, 256, 0, stream>>>(X, src, dst, sumnb, cnt_dst, cnt_src);
    }
    // pass 2: fused SAGE + projections
    node_pass<<<2048, 256, 0, stream>>>(X, sumnb, cnt_dst, Wself, Wneigh, bsage,
                                        Qw, A, B);
    // pass 3: edge scores, scatter-sum by src into out
    {
        long long threads = (long long)NE * 64;
        int blocks = (int)((threads + 255) / 256);
        edge_pass<<<blocks, 256, 0, stream>>>(A, B, Qb, src, dst, out);
    }
    // pass 4: mean + tanh
    finalize<<<(NN * NH + 255) / 256, 256, 0, stream>>>(out, cnt_src);
}